// Round 6
// baseline (284.283 us; speedup 1.0000x reference)
//
#include <hip/hip_runtime.h>

typedef short v8s __attribute__((ext_vector_type(8)));
typedef float v4f __attribute__((ext_vector_type(4)));

#define BH 16384             // B*H
#define TBH 33554432         // T*B*H
#define SEG 16               // segments over T
#define SEGT 128             // timesteps per segment (2048/16)
#define SCAN_TILE 128        // (fallback scan) timesteps per LDS tile
#define NTILE 16             // 2048 / 128

__device__ __forceinline__ ushort f2bf(float f) {
  // round-to-nearest-even fp32 -> bf16 (inputs finite, no NaN handling needed)
  uint u = __float_as_uint(f);
  u += 0x7FFF + ((u >> 16) & 1);
  return (ushort)(u >> 16);
}

// pack 2 fp32 -> 2 bf16 in one uint via the HW pack-convert (RTNE, matches f2bf)
__device__ __forceinline__ uint pkbf2(float a, float b) {
  uint r;
  asm("v_cvt_pk_bf16_f32 %0, %1, %2" : "=v"(r) : "v"(a), "v"(b));
  return r;
}

union frag_u { uint u[4]; v8s s; };

// ---------------- Phase 0: W fp32 -> bf16, pre-swizzled, BK=32 chunk layout ----------
// Wbf[c(0..7)][row(0..255)][sp(0..3)] 16B slots; phys slot sp holds logical slot
// s = sp ^ ((row>>1)&3), i.e. W[row][c*32 + s*8 .. +7]. Gemm stages each chunk with
// fully linear global_load_lds and reads LDS at sp = lhi ^ ((row>>1)&3):
// slot%8 = (4*row + sp) % 8 runs through all 8 bank-groups over 8 rows -> 2-way (free).
__global__ __launch_bounds__(256) void indrnn_w2bf(
    const float* __restrict__ W, ushort* __restrict__ Wbf)
{
  const int g   = blockIdx.x * 256 + threadIdx.x;   // 8192 slots total
  const int c   = g >> 10;
  const int rem = g & 1023;
  const int row = rem >> 2;
  const int sp  = rem & 3;
  const int s   = sp ^ ((row >> 1) & 3);
  const float* src = W + row * 256 + c * 32 + s * 8;
  const float4 f0 = *(const float4*)src;
  const float4 f1 = *(const float4*)(src + 4);
  uint4 o;
  o.x = pkbf2(f0.x, f0.y); o.y = pkbf2(f0.z, f0.w);
  o.z = pkbf2(f1.x, f1.y); o.w = pkbf2(f1.z, f1.w);
  *(uint4*)(Wbf + (size_t)g * 8) = o;
}

// ---------------- Phase 1: xW[m,h] = sum_i x[m,i] * W[h,i], bf16 MFMA ----------------
// v4: double-buffered DMA pipeline with counted vmcnt (T3+T4 minimum recipe).
//   BM=64, BN=256, BK=32, 8 chunks; LDS 2 x (8KB A + 16KB W) = 48 KB -> 3 blocks/CU.
//   Per chunk each wave issues exactly 6 global_load_lds (2 A + 4 W); steady-state
//   wait is vmcnt(6) (next chunk in flight across barriers), vmcnt(0) only at tail.
//   A staged raw fp32 w/ XOR-swizzled source (slot ^= row&7); W from pre-swizzled Wbf.
__global__ __launch_bounds__(256, 3) void indrnn_gemm(
    const float* __restrict__ A,
    const ushort* __restrict__ Wbf,
    ushort* __restrict__ C)
{
  __shared__ __align__(16) float  Af[2][2048];   // 2 x 64 rows x 8 slots x 4 fp32
  __shared__ __align__(16) ushort Bs[2][8192];   // 2 x 256 rows x 4 slots x 8 bf16

  const int tid  = threadIdx.x;
  const int lane = tid & 63;
  const int wn   = tid >> 6;      // 0..3 -> 64-col slice of H
  const int l15  = lane & 15;
  const int lhi  = lane >> 4;     // 0..3
  const int m0   = blockIdx.x * 64;
  const int bfl  = tid & 192;     // wave base slot offset

  auto stageA = [&](int c, int buf) {
    #pragma unroll
    for (int j = 0; j < 2; ++j) {
      const int bf_ = j * 256 + bfl;            // wave-uniform slot base
      const int fl  = bf_ + lane;               // slot = row*8 + sl
      const int row = fl >> 3;
      const int sl  = fl & 7;
      const float* src = A + ((size_t)(m0 + row) << 8) + c * 32 + ((sl ^ (row & 7)) << 2);
      __builtin_amdgcn_global_load_lds(src, &Af[buf][bf_ << 2], 16, 0, 0);
    }
  };
  auto stageW = [&](int c, int buf) {
    #pragma unroll
    for (int j = 0; j < 4; ++j) {
      const int bf_ = j * 256 + bfl;
      const int fl  = bf_ + lane;               // linear slot in pre-swizzled Wbf
      __builtin_amdgcn_global_load_lds(
          (const float*)(Wbf + (size_t)c * 8192 + (size_t)fl * 8),
          (float*)(&Bs[buf][bf_ * 8]), 16, 0, 0);
    }
  };

  v4f acc[4][4] = {};

  stageA(0, 0); stageW(0, 0);

  auto step = [&](int c, int buf) {
    if (c + 1 < 8) {
      stageA(c + 1, buf ^ 1);                   // next chunk in flight
      stageW(c + 1, buf ^ 1);
      asm volatile("s_waitcnt vmcnt(6)" ::: "memory");   // chunk c complete
    } else {
      asm volatile("s_waitcnt vmcnt(0)" ::: "memory");   // tail drain
    }
    __builtin_amdgcn_s_barrier();               // all waves see chunk c
    __builtin_amdgcn_sched_barrier(0);

    v8s bfr[4];
    #pragma unroll
    for (int nt = 0; nt < 4; ++nt) {
      const int row = wn * 64 + nt * 16 + l15;
      const int sp  = lhi ^ ((row >> 1) & 3);
      bfr[nt] = *(const v8s*)(&Bs[buf][row * 32 + sp * 8]);
    }
    #pragma unroll
    for (int mt = 0; mt < 4; ++mt) {
      const int row = mt * 16 + l15;
      const int p0  = (2 * lhi) ^ (row & 7);
      const int p1  = (2 * lhi + 1) ^ (row & 7);
      const float4 lo = *(const float4*)(&Af[buf][row * 32 + p0 * 4]);
      const float4 hi = *(const float4*)(&Af[buf][row * 32 + p1 * 4]);
      frag_u t;
      t.u[0] = pkbf2(lo.x, lo.y); t.u[1] = pkbf2(lo.z, lo.w);
      t.u[2] = pkbf2(hi.x, hi.y); t.u[3] = pkbf2(hi.z, hi.w);
      #pragma unroll
      for (int nt = 0; nt < 4; ++nt)
        acc[mt][nt] = __builtin_amdgcn_mfma_f32_16x16x32_bf16(t.s, bfr[nt], acc[mt][nt], 0, 0, 0);
    }
    __builtin_amdgcn_sched_barrier(0);
    __builtin_amdgcn_s_barrier();               // done reading buf -> reusable
  };

  for (int cc = 0; cc < 8; cc += 2) {
    step(cc,     0);
    step(cc + 1, 1);
  }

  // epilogue: C/D layout col=lane&15, row=(lane>>4)*4+reg
  #pragma unroll
  for (int mt = 0; mt < 4; ++mt) {
    #pragma unroll
    for (int nt = 0; nt < 4; ++nt) {
      #pragma unroll
      for (int r = 0; r < 4; ++r) {
        int row = m0 + mt * 16 + lhi * 4 + r;
        int col = wn * 64 + nt * 16 + l15;
        C[((size_t)row << 8) + col] = f2bf(acc[mt][nt][r]);
      }
    }
  }
}

// ---------------- Phase 2a: per-segment transfer functions ----------------
// IndRNN step f(h)=max(0, x + w*h) preserves the family F(h)=clamp(p*h+a, lo, hi).
// Compose 128 steps per (seg, ch); write (p,a,lo,hi). 1024 blocks -> 16 waves/CU.
__global__ __launch_bounds__(256) void indrnn_seg(
    const ushort* __restrict__ xw,
    const float* __restrict__ w_hh,
    float4* __restrict__ fn)
{
  const int chgrp = blockIdx.x & 63;
  const int seg   = blockIdx.x >> 6;
  const int ch    = chgrp * 256 + threadIdx.x;
  const float w   = w_hh[ch & 255];
  const ushort* px = xw + (size_t)seg * SEGT * BH + ch;

  float p = 1.0f, a = 0.0f, lo = -3.402823466e38f, hi = 3.402823466e38f;

  uint b0[16], b1[16];
  auto ldb = [&](uint (&buf)[16], int kb) {
    const ushort* q = px + (size_t)kb * 16 * BH;
    #pragma unroll
    for (int j = 0; j < 16; ++j) buf[j] = q[(size_t)j * BH];
  };
  auto comp = [&](uint (&buf)[16]) {
    #pragma unroll
    for (int j = 0; j < 16; ++j) {
      float xv = __uint_as_float(buf[j] << 16);
      float A = fmaf(w, lo, xv);
      float B = fmaf(w, hi, xv);
      lo = fmaxf(0.0f, fminf(A, B));
      hi = fmaxf(0.0f, fmaxf(A, B));
      a  = fmaf(w, a, xv);
      p *= w;
    }
  };

  ldb(b0, 0); ldb(b1, 1);
  for (int kb = 0; kb < 8; kb += 2) {
    comp(b0); if (kb + 2 < 8) ldb(b0, kb + 2);
    comp(b1); if (kb + 3 < 8) ldb(b1, kb + 3);
  }
  fn[(size_t)seg * BH + ch] = make_float4(p, a, lo, hi);
}

// ---------------- Phase 2b: prefix-compose h_in, then re-scan + store ----------------
__global__ __launch_bounds__(256) void indrnn_fix(
    const ushort* __restrict__ xw,
    const float* __restrict__ h0,
    const float* __restrict__ w_hh,
    const float4* __restrict__ fn,
    float* __restrict__ out)
{
  const int chgrp = blockIdx.x & 63;
  const int seg   = blockIdx.x >> 6;
  const int ch    = chgrp * 256 + threadIdx.x;
  const float w   = w_hh[ch & 255];

  // exact segment-entry state via <=15 clamp-affine compositions (wave-uniform bound)
  float h = h0[ch];
  for (int s = 0; s < seg; ++s) {
    const float4 F = fn[(size_t)s * BH + ch];
    h = fminf(fmaxf(fmaf(F.x, h, F.y), F.z), F.w);
  }

  const ushort* px = xw + (size_t)seg * SEGT * BH + ch;
  float*        po = out + (size_t)seg * SEGT * BH + ch;

  uint b0[16], b1[16];
  auto ldb = [&](uint (&buf)[16], int kb) {
    const ushort* q = px + (size_t)kb * 16 * BH;
    #pragma unroll
    for (int j = 0; j < 16; ++j) buf[j] = q[(size_t)j * BH];
  };
  auto cp = [&](uint (&buf)[16], int kb) {
    float* o = po + (size_t)kb * 16 * BH;
    #pragma unroll
    for (int j = 0; j < 16; ++j) {
      float xv = __uint_as_float(buf[j] << 16);
      h = fmaxf(fmaf(h, w, xv), 0.0f);
      o[(size_t)j * BH] = h;
    }
  };

  ldb(b0, 0); ldb(b1, 1);
  for (int kb = 0; kb < 8; kb += 2) {
    cp(b0, kb);     if (kb + 2 < 8) ldb(b0, kb + 2);
    cp(b1, kb + 1); if (kb + 3 < 8) ldb(b1, kb + 3);
  }

  if (seg == SEG - 1) out[(size_t)TBH + ch] = h;
}

// ---------------- Fallbacks (workspace-tight path): r0 gemm + r3 scan ----------------
__global__ __launch_bounds__(512) void indrnn_gemm_fb(
    const float* __restrict__ A,
    const float* __restrict__ W,
    ushort* __restrict__ C)
{
  __shared__ ushort As[128 * 72];
  __shared__ ushort Bs[256 * 72];

  const int tid  = threadIdx.x;
  const int lane = tid & 63;
  const int wid  = tid >> 6;
  const int wm   = wid >> 2;
  const int wn   = wid & 3;
  const int m0   = blockIdx.x * 128;
  const int l15 = lane & 15;
  const int lhi = lane >> 4;

  v4f acc[4][4] = {};

  for (int kc = 0; kc < 4; ++kc) {
    #pragma unroll
    for (int j = 0; j < 4; ++j) {
      int f    = j * 512 + tid;
      int row  = f >> 4;
      int colf = f & 15;
      const float4 a4 = *(const float4*)(A + ((size_t)(m0 + row) << 8) + kc * 64 + colf * 4);
      ushort4 b4 = make_ushort4(f2bf(a4.x), f2bf(a4.y), f2bf(a4.z), f2bf(a4.w));
      *(ushort4*)(As + row * 72 + colf * 4) = b4;
    }
    #pragma unroll
    for (int j = 0; j < 8; ++j) {
      int f    = j * 512 + tid;
      int row  = f >> 4;
      int colf = f & 15;
      const float4 a4 = *(const float4*)(W + ((size_t)row << 8) + kc * 64 + colf * 4);
      ushort4 b4 = make_ushort4(f2bf(a4.x), f2bf(a4.y), f2bf(a4.z), f2bf(a4.w));
      *(ushort4*)(Bs + row * 72 + colf * 4) = b4;
    }
    __syncthreads();

    #pragma unroll
    for (int kk = 0; kk < 2; ++kk) {
      const int koff = kk * 32 + lhi * 8;
      v8s af[4], bf[4];
      #pragma unroll
      for (int mt = 0; mt < 4; ++mt)
        af[mt] = *(const v8s*)(As + (wm * 64 + mt * 16 + l15) * 72 + koff);
      #pragma unroll
      for (int nt = 0; nt < 4; ++nt)
        bf[nt] = *(const v8s*)(Bs + (wn * 64 + nt * 16 + l15) * 72 + koff);
      #pragma unroll
      for (int mt = 0; mt < 4; ++mt)
        #pragma unroll
        for (int nt = 0; nt < 4; ++nt)
          acc[mt][nt] = __builtin_amdgcn_mfma_f32_16x16x32_bf16(af[mt], bf[nt], acc[mt][nt], 0, 0, 0);
    }
    __syncthreads();
  }

  #pragma unroll
  for (int mt = 0; mt < 4; ++mt)
    #pragma unroll
    for (int nt = 0; nt < 4; ++nt)
      #pragma unroll
      for (int r = 0; r < 4; ++r) {
        int row = m0 + wm * 64 + mt * 16 + lhi * 4 + r;
        int col = wn * 64 + nt * 16 + l15;
        C[((size_t)row << 8) + col] = f2bf(acc[mt][nt][r]);
      }
}

__global__ __launch_bounds__(128) void indrnn_scan(
    const ushort* __restrict__ xw,
    const float* __restrict__ h0,
    const float* __restrict__ w_hh,
    float* __restrict__ out)
{
  __shared__ __align__(16) ushort tile[3][SCAN_TILE * 64];

  const int lane = threadIdx.x & 63;
  const int wv   = threadIdx.x >> 6;
  const int ch0  = blockIdx.x * 64;
  const int ch   = ch0 + lane;

  const size_t psrc0 = (size_t)(lane >> 3) * BH + (size_t)ch0 + ((lane & 7) << 3);

  auto stage = [&](int ti) {
    const ushort* src = xw + (size_t)ti * SCAN_TILE * BH + psrc0;
    ushort* dst = &tile[ti % 3][0];
    #pragma unroll
    for (int j = 0; j < 16; ++j) {
      __builtin_amdgcn_global_load_lds(
          (const float*)(src + (size_t)j * 8 * BH),
          (float*)(dst + j * 512), 16, 0, 0);
    }
  };

  float h = 0.0f, w = 0.0f;
  if (wv == 0) {
    h = h0[ch];
    w = w_hh[ch & 255];
  } else {
    stage(0);
    stage(1);
    asm volatile("s_waitcnt vmcnt(16)" ::: "memory");
  }
  asm volatile("" ::: "memory");
  __builtin_amdgcn_s_barrier();
  __builtin_amdgcn_sched_barrier(0);

  for (int i = 0; i < NTILE; ++i) {
    if (wv == 0) {
      const ushort* tp = &tile[i % 3][lane];
      float* po = out + (size_t)i * SCAN_TILE * BH + ch;
      #pragma unroll
      for (int t = 0; t < SCAN_TILE; t += 16) {
        ushort v[16];
        #pragma unroll
        for (int j = 0; j < 16; ++j) v[j] = tp[(t + j) * 64];
        #pragma unroll
        for (int j = 0; j < 16; ++j) {
          float xv = __uint_as_float((uint)v[j] << 16);
          h = fmaxf(fmaf(h, w, xv), 0.0f);
          po[(size_t)(t + j) * BH] = h;
        }
      }
    } else {
      if (i + 2 < NTILE) {
        stage(i + 2);
        asm volatile("s_waitcnt vmcnt(16)" ::: "memory");
      } else {
        asm volatile("s_waitcnt vmcnt(0)" ::: "memory");
      }
    }
    asm volatile("" ::: "memory");
    __builtin_amdgcn_s_barrier();
    __builtin_amdgcn_sched_barrier(0);
  }

  if (wv == 0) out[(size_t)TBH + ch] = h;
}

extern "C" void kernel_launch(void* const* d_in, const int* in_sizes, int n_in,
                              void* d_out, int out_size, void* d_ws, size_t ws_size,
                              hipStream_t stream) {
  const float* x    = (const float*)d_in[0];   // [2048, 64, 256]
  const float* h0   = (const float*)d_in[1];   // [1, 64, 256]
  const float* W_ih = (const float*)d_in[2];   // [256, 256]
  const float* w_hh = (const float*)d_in[3];   // [256]
  float* out = (float*)d_out;                  // [T,B,H] ++ [1,B,H]
  ushort* xw = (ushort*)d_ws;                  // bf16 intermediate, 64 MiB

  const size_t off_fn = 64ull << 20;                                  // 64 MiB
  const size_t off_wb = off_fn + (size_t)SEG * BH * sizeof(float4);   // +4 MiB
  const size_t need   = off_wb + 131072;                              // +128 KiB

  if (ws_size >= need) {
    float4* fn  = (float4*)((char*)d_ws + off_fn);
    ushort* wbf = (ushort*)((char*)d_ws + off_wb);
    indrnn_w2bf<<<dim3(32),   dim3(256), 0, stream>>>(W_ih, wbf);
    indrnn_gemm<<<dim3(2048), dim3(256), 0, stream>>>(x, wbf, xw);
    indrnn_seg <<<dim3(1024), dim3(256), 0, stream>>>(xw, w_hh, fn);
    indrnn_fix <<<dim3(1024), dim3(256), 0, stream>>>(xw, h0, w_hh, fn, out);
  } else {
    indrnn_gemm_fb<<<dim3(1024), dim3(512), 0, stream>>>(x, W_ih, xw);
    indrnn_scan<<<dim3(256), dim3(128), 0, stream>>>(xw, h0, w_hh, out);
  }
}